// Round 6
// baseline (3042.168 us; speedup 1.0000x reference)
//
#include <hip/hip_runtime.h>
#include <stdint.h>

#define TSTEPS 50
#define BATCH  1024
#define INDIM  405
#define KP     448      // padded K for gx GEMM (7 x 64)
#define HDIM   200
#define G4H    800      // 4*H
#define NMEM   128
#define DMEM   40
#define DPAD   44       // sM row stride: 16B-aligned
#define RH     4
#define RD     160      // RH*DMEM
#define NWAY   5
#define GAMMA_ 0.99f
#define NG     2        // batches per block (512 blocks -> 2 blocks/CU)
#define WROWS  928      // gx GEMM W rows padded

typedef __attribute__((ext_vector_type(8))) short short8;
typedef __attribute__((ext_vector_type(4))) float f32x4;

__device__ __forceinline__ float sigmoidf_(float x) {
    return 1.f / (1.f + __expf(-x));
}
__device__ __forceinline__ float ftanh(float x) {
    float e = __expf(2.f * x);
    return 1.f - 2.f / (e + 1.f);
}
__device__ __forceinline__ unsigned short f2bf(float f) {   // RNE f32->bf16
    uint32_t u = __float_as_uint(f);
    uint32_t r = u + 0x7FFFu + ((u >> 16) & 1u);
    return (unsigned short)(r >> 16);
}
__device__ __forceinline__ float bf2f(unsigned short h) {
    return __uint_as_float(((uint32_t)h) << 16);
}

// ---- recurrent weights -> bf16 TRANSPOSED (WhhT[j][o], WkT[j][rd]) --------
__global__ __launch_bounds__(256) void convert_recT(const float* __restrict__ W_hh,
                                                    const float* __restrict__ Wk,
                                                    unsigned short* __restrict__ WhhT_bf,
                                                    unsigned short* __restrict__ WkT_bf) {
    int i = blockIdx.x * 256 + threadIdx.x;
    if (i < HDIM * G4H) {
        int j = i / G4H, o = i % G4H;
        WhhT_bf[i] = f2bf(W_hh[o * HDIM + j]);
    } else if (i < HDIM * G4H + HDIM * RD) {
        int e = i - HDIM * G4H;
        int j = e / RD, rd = e % RD;
        WkT_bf[e] = f2bf(Wk[rd * HDIM + j]);
    }
}

// ---------------- split f32 -> (hi, lo) bf16, zero-padded K (gx GEMM) ------
__global__ __launch_bounds__(256) void convert_A(const float* __restrict__ x,
                                                 unsigned short* __restrict__ Ahi,
                                                 unsigned short* __restrict__ Alo) {
    int c = blockIdx.x * 256 + threadIdx.x;
    int r = blockIdx.y;
    if (c >= KP) return;
    float v = (c < INDIM) ? x[(size_t)r * INDIM + c] : 0.f;
    unsigned short hi = f2bf(v);
    unsigned short lo = f2bf(v - bf2f(hi));
    size_t o = (size_t)r * KP + c;
    Ahi[o] = hi;
    Alo[o] = lo;
}

__global__ __launch_bounds__(256) void convert_W(const float* __restrict__ W_ih,
                                                 unsigned short* __restrict__ Wpk) {
    int c = blockIdx.x * 256 + threadIdx.x;
    int n = blockIdx.y;
    int sec = blockIdx.z;
    if (c >= KP) return;
    float v = (n < G4H && c < INDIM) ? W_ih[(size_t)n * INDIM + c] : 0.f;
    unsigned short hi = f2bf(v);
    size_t o = (size_t)sec * WROWS * KP + (size_t)n * KP + c;
    Wpk[o] = (sec == 0) ? hi : f2bf(v - bf2f(hi));
}

// ---------------- gx GEMM via 3-term split-bf16 MFMA ----------------------
__global__ __launch_bounds__(256) void gx_gemm_mfma(
        const unsigned short* __restrict__ Ahi,
        const unsigned short* __restrict__ Alo,
        const unsigned short* __restrict__ Wpk,
        const float* __restrict__ b_ih, const float* __restrict__ b_hh,
        float* __restrict__ gx) {
    __shared__ unsigned short Alds[128 * 64];
    __shared__ unsigned short Blds[128 * 64];
    const int tid = threadIdx.x;
    const int wv = tid >> 6, ln = tid & 63;
    const int wr = wv >> 1, wc = wv & 1;
    const int n0 = blockIdx.x * 128;
    const int m0 = blockIdx.y * 128;

    f32x4 acc[4][4];
#pragma unroll
    for (int m = 0; m < 4; ++m)
#pragma unroll
        for (int n = 0; n < 4; ++n) acc[m][n] = (f32x4){0.f, 0.f, 0.f, 0.f};

    int erow[4], ecol[4];
#pragma unroll
    for (int i = 0; i < 4; ++i) {
        int e = (i * 4 + wv) * 512 + ln * 8;
        erow[i] = e >> 6;
        ecol[i] = e & 63;
    }

    const unsigned short* Whi = Wpk;
    const unsigned short* Wlo = Wpk + (size_t)WROWS * KP;

#pragma unroll 1
    for (int s = 0; s < 3; ++s) {
        const unsigned short* Ab = ((s == 2) ? Alo : Ahi) + (size_t)m0 * KP;
        const unsigned short* Bb = ((s == 1) ? Wlo : Whi) + (size_t)n0 * KP;

        short8 ar[4], br[4];
#pragma unroll
        for (int i = 0; i < 4; ++i) {
            ar[i] = *(const short8*)&Ab[(size_t)erow[i] * KP + ecol[i]];
            br[i] = *(const short8*)&Bb[(size_t)erow[i] * KP + ecol[i]];
        }

#pragma unroll 1
        for (int k0 = 0; k0 < KP; k0 += 64) {
            __syncthreads();
#pragma unroll
            for (int i = 0; i < 4; ++i) {
                int e = (i * 4 + wv) * 512 + ln * 8;
                *(short8*)&Alds[e] = ar[i];
                *(short8*)&Blds[e] = br[i];
            }
            __syncthreads();
            if (k0 + 64 < KP) {
#pragma unroll
                for (int i = 0; i < 4; ++i) {
                    ar[i] = *(const short8*)&Ab[(size_t)erow[i] * KP + k0 + 64 + ecol[i]];
                    br[i] = *(const short8*)&Bb[(size_t)erow[i] * KP + k0 + 64 + ecol[i]];
                }
            }
#pragma unroll
            for (int ks = 0; ks < 2; ++ks) {
                short8 af[4], bf[4];
                int kcol = ks * 32 + (ln >> 4) * 8;
#pragma unroll
                for (int m = 0; m < 4; ++m) {
                    int row = wr * 64 + m * 16 + (ln & 15);
                    af[m] = *(const short8*)&Alds[row * 64 + kcol];
                }
#pragma unroll
                for (int n = 0; n < 4; ++n) {
                    int row = wc * 64 + n * 16 + (ln & 15);
                    bf[n] = *(const short8*)&Blds[row * 64 + kcol];
                }
#pragma unroll
                for (int m = 0; m < 4; ++m)
#pragma unroll
                    for (int n = 0; n < 4; ++n)
                        acc[m][n] = __builtin_amdgcn_mfma_f32_16x16x32_bf16(
                            af[m], bf[n], acc[m][n], 0, 0, 0);
            }
        }
    }

#pragma unroll
    for (int n = 0; n < 4; ++n) {
        int col = n0 + wc * 64 + n * 16 + (ln & 15);
        if (col >= G4H) continue;
        float bias = b_ih[col] + b_hh[col];
#pragma unroll
        for (int m = 0; m < 4; ++m) {
#pragma unroll
            for (int j = 0; j < 4; ++j) {
                int row = m0 + wr * 64 + m * 16 + (ln >> 4) * 4 + j;
                gx[(size_t)row * G4H + col] = acc[m][n][j] + bias;
            }
        }
    }
}

// ---------------- f32 fallback GEMM ---------------------------------------
__global__ __launch_bounds__(256) void gx_gemm(const float* __restrict__ x,
                                               const float* __restrict__ W_ih,
                                               const float* __restrict__ b_ih,
                                               const float* __restrict__ b_hh,
                                               float* __restrict__ gx) {
    const int BM = 128, BN = 80, BK = 16;
    __shared__ float As[BK][BM];
    __shared__ float Bs[BK][BN];
    int m0 = blockIdx.y * BM;
    int n0 = blockIdx.x * BN;
    int tid = threadIdx.x;
    int tm = tid >> 4, tn = tid & 15;
    float acc[8][5];
#pragma unroll
    for (int i = 0; i < 8; ++i)
#pragma unroll
        for (int j = 0; j < 5; ++j) acc[i][j] = 0.f;

    for (int k0 = 0; k0 < INDIM; k0 += BK) {
        {
            int row = tid >> 1, kk = (tid & 1) * 8;
            const float* ap = x + (size_t)(m0 + row) * INDIM + k0 + kk;
#pragma unroll
            for (int i = 0; i < 8; ++i)
                As[kk + i][row] = (k0 + kk + i < INDIM) ? ap[i] : 0.f;
        }
        if (tid < 160) {
            int col = tid >> 1, kk = (tid & 1) * 8;
            const float* bp = W_ih + (size_t)(n0 + col) * INDIM + k0 + kk;
#pragma unroll
            for (int i = 0; i < 8; ++i)
                Bs[kk + i][col] = (k0 + kk + i < INDIM) ? bp[i] : 0.f;
        }
        __syncthreads();
#pragma unroll
        for (int k = 0; k < BK; ++k) {
            float a[8], b[5];
#pragma unroll
            for (int i = 0; i < 8; ++i) a[i] = As[k][tm * 8 + i];
#pragma unroll
            for (int j = 0; j < 5; ++j) b[j] = Bs[k][tn * 5 + j];
#pragma unroll
            for (int i = 0; i < 8; ++i)
#pragma unroll
                for (int j = 0; j < 5; ++j) acc[i][j] += a[i] * b[j];
        }
        __syncthreads();
    }
#pragma unroll
    for (int j = 0; j < 5; ++j) {
        int n = n0 + tn * 5 + j;
        float bias = b_ih[n] + b_hh[n];
#pragma unroll
        for (int i = 0; i < 8; ++i) {
            int m = m0 + tm * 8 + i;
            gx[(size_t)m * G4H + n] = acc[i][j] + bias;
        }
    }
}

// ---------------- persistent NTM scan: NG=2, 2 blocks/CU -------------------
__global__ __launch_bounds__(1024, 8) void ntm_scan(
        const float* __restrict__ gx,               // [T][B][800]
        const unsigned short* __restrict__ WhhT_bf, // [200][800] bf16
        const unsigned short* __restrict__ WkT_bf,  // [200][160] bf16
        const float* __restrict__ bk,
        const float* __restrict__ Wsm,              // [4][200]
        const float* __restrict__ bs,
        const float* __restrict__ Wo,               // [5][360]
        const float* __restrict__ bo,
        float* __restrict__ out) {                  // [T][B][5]
    __shared__ float sM[NG][NMEM][DPAD];     // 45 KB
    __shared__ float sh[NG][HDIM];
    __shared__ float sgate[NG][G4H];
    __shared__ float spartK[NG][4][RD];
    __shared__ float spartS[NG][RH][4];
    __shared__ float swr[NG][RH][NMEM];
    __shared__ float sww[NG][RH][NMEM];
    __shared__ float sKs[NG][RH][NMEM];
    __shared__ float swu[NG][NMEM];
    __shared__ float swlu[NG][NMEM];
    __shared__ float sk[NG][RH][DMEM];
    __shared__ float sr[NG][RD];
    __shared__ float snk[NG][RH];
    __shared__ float ssig[NG][RH];
    __shared__ float snM[NG][NMEM];
    __shared__ float stmp[NG][NWAY];
    __shared__ int   sidx[NG];

    const int tid = threadIdx.x;
    const int b0  = blockIdx.x * NG;
    const int w   = tid >> 6, l = tid & 63;

    // ---- init carries ----
    for (int e = tid; e < NG * NMEM * DPAD; e += 1024) ((float*)sM)[e] = 0.f;
    for (int e = tid; e < NG * HDIM; e += 1024) ((float*)sh)[e] = 0.f;
    for (int e = tid; e < NG * RH * NMEM; e += 1024) ((float*)swr)[e] = 0.f;
    for (int e = tid; e < NG * NMEM; e += 1024) { ((float*)swu)[e] = 0.f; ((float*)swlu)[e] = 1.f; }

    float c_reg = 0.f;   // thread tid<400 owns (batch tid/200, unit tid%200)
    float gxr0 = 0.f, gxr1 = 0.f;
    if (tid < G4H) {
        const float* gxp = gx + (size_t)b0 * G4H + tid;
        gxr0 = gxp[0]; gxr1 = gxp[G4H];
    }
    __syncthreads();

    for (int t = 0; t < TSTEPS; ++t) {
        // ---- A: gates = gx + h @ WhhT (800 thr, bf16 weights, 2 batches) ----
        if (tid < G4H) {
            const int o = tid;
            const unsigned short* wp = WhhT_bf + o;
            float acc0 = 0.f, acc1 = 0.f;
#pragma unroll 2
            for (int j = 0; j < HDIM; j += 4) {
                float4 h0 = *(const float4*)&sh[0][j];
                float4 h1 = *(const float4*)&sh[1][j];
                float w0 = bf2f(wp[(j + 0) * G4H]);
                float w1 = bf2f(wp[(j + 1) * G4H]);
                float w2 = bf2f(wp[(j + 2) * G4H]);
                float w3 = bf2f(wp[(j + 3) * G4H]);
                acc0 += w0 * h0.x + w1 * h0.y + w2 * h0.z + w3 * h0.w;
                acc1 += w0 * h1.x + w1 * h1.y + w2 * h1.z + w3 * h1.w;
            }
            sgate[0][o] = acc0 + gxr0;
            sgate[1][o] = acc1 + gxr1;
            if (t + 1 < TSTEPS) {   // prefetch next step's gx
                const float* gxp = gx + ((size_t)(t + 1) * BATCH + b0) * G4H + o;
                gxr0 = gxp[0]; gxr1 = gxp[G4H];
            }
        }
        __syncthreads();

        // ---- B: LSTM cell; c in registers ----
        if (tid < NG * HDIM) {
            int gg = tid / HDIM, j = tid - gg * HDIM;
            float ig = sigmoidf_(sgate[gg][j]);
            float fg = sigmoidf_(sgate[gg][j + HDIM]);
            float gv = ftanh(sgate[gg][j + 2 * HDIM]);
            float og = sigmoidf_(sgate[gg][j + 3 * HDIM]);
            c_reg = fg * c_reg + ig * gv;
            sh[gg][j] = og * ftanh(c_reg);
        }
        __syncthreads();

        // ---- C: key partials (640) | sigma partials (32) | argmin wu (128) ----
        if (tid < 640) {
            int col = tid % RD, c = tid / RD;     // 4 K-chunks
            int jb = 52 * c - ((c == 3) ? 4 : 0);
            int je = jb + ((c < 2) ? 52 : 48);
            const unsigned short* wp = WkT_bf + col;
            float a0 = 0.f, a1 = 0.f;
            for (int j = jb; j < je; j += 4) {
                float4 h0 = *(const float4*)&sh[0][j];
                float4 h1 = *(const float4*)&sh[1][j];
                float w0 = bf2f(wp[(j + 0) * RD]);
                float w1 = bf2f(wp[(j + 1) * RD]);
                float w2 = bf2f(wp[(j + 2) * RD]);
                float w3 = bf2f(wp[(j + 3) * RD]);
                a0 += w0 * h0.x + w1 * h0.y + w2 * h0.z + w3 * h0.w;
                a1 += w0 * h1.x + w1 * h1.y + w2 * h1.z + w3 * h1.w;
            }
            spartK[0][c][col] = a0;
            spartK[1][c][col] = a1;
        } else if (tid < 672) {
            int v = tid - 640; int g = v >> 4, rc = v & 15, r = rc >> 2, cc = rc & 3;
            const float* wrow = Wsm + r * HDIM;
            float a = 0.f;
            for (int j = 50 * cc; j < 50 * cc + 50; ++j) a += sh[g][j] * wrow[j];
            spartS[g][r][cc] = a;
        } else if (tid >= 704 && tid < 832) {
            int a = tid - 704; int g = a >> 6, ln = a & 63;  // waves 11,12
            float v0 = swu[g][ln], v1 = swu[g][ln + 64];
            bool p1 = (v1 < v0);
            float mv = p1 ? v1 : v0;
            int   mi = p1 ? ln + 64 : ln;
#pragma unroll
            for (int off = 32; off; off >>= 1) {
                float ov = __shfl_xor(mv, off);
                int   oi = __shfl_xor(mi, off);
                if (ov < mv || (ov == mv && oi < mi)) { mv = ov; mi = oi; }
            }
            if (ln == 0) sidx[g] = mi;
        }
        __syncthreads();

        // ---- D: finalize k (320) | finalize sigma (8) ----
        if (tid < 320) {
            int g = tid / RD, col = tid % RD;
            float s = spartK[g][0][col] + spartK[g][1][col]
                    + spartK[g][2][col] + spartK[g][3][col] + bk[col];
            sk[g][col / DMEM][col % DMEM] = ftanh(s);
        } else if (tid < 328) {
            int v = tid - 320; int g = v >> 2, r = v & 3;
            float s = spartS[g][r][0] + spartS[g][r][1]
                    + spartS[g][r][2] + spartS[g][r][3] + bs[r];
            ssig[g][r] = sigmoidf_(ftanh(s));
        }
        __syncthreads();

        // ---- E2': ww + zero-LU-row + rank-4 M update (512) | ||k|| (8) ----
        if (tid < 512) {
            int g = tid >> 8, mh = tid & 255, m = mh >> 1, dh = mh & 1;
            float sg0 = ssig[g][0], sg1 = ssig[g][1], sg2 = ssig[g][2], sg3 = ssig[g][3];
            float wl = swlu[g][m];
            float w0 = sg0 * swr[g][0][m] + (1.f - sg0) * wl;
            float w1 = sg1 * swr[g][1][m] + (1.f - sg1) * wl;
            float w2 = sg2 * swr[g][2][m] + (1.f - sg2) * wl;
            float w3 = sg3 * swr[g][3][m] + (1.f - sg3) * wl;
            if (!dh) {
                sww[g][0][m] = w0; sww[g][1][m] = w1;
                sww[g][2][m] = w2; sww[g][3][m] = w3;
            }
            bool zr = (m == sidx[g]);
            int d0 = dh * 20;
#pragma unroll
            for (int q = 0; q < 5; ++q) {
                int d = d0 + q * 4;
                float4 mv = *(const float4*)&sM[g][m][d];
                float4 k0 = *(const float4*)&sk[g][0][d];
                float4 k1 = *(const float4*)&sk[g][1][d];
                float4 k2 = *(const float4*)&sk[g][2][d];
                float4 k3 = *(const float4*)&sk[g][3][d];
                float4 o;
                o.x = (zr ? 0.f : mv.x) + w0 * k0.x + w1 * k1.x + w2 * k2.x + w3 * k3.x;
                o.y = (zr ? 0.f : mv.y) + w0 * k0.y + w1 * k1.y + w2 * k2.y + w3 * k3.y;
                o.z = (zr ? 0.f : mv.z) + w0 * k0.z + w1 * k1.z + w2 * k2.z + w3 * k3.z;
                o.w = (zr ? 0.f : mv.w) + w0 * k0.w + w1 * k1.w + w2 * k2.w + w3 * k3.w;
                *(float4*)&sM[g][m][d] = o;
            }
        } else if (tid < 520) {
            int v = tid - 512; int g2 = v >> 2, r2 = v & 3;
            float a0 = 0.f, a1 = 0.f, a2 = 0.f, a3 = 0.f;
#pragma unroll
            for (int q = 0; q < 10; ++q) {
                float4 kv = *(const float4*)&sk[g2][r2][q * 4];
                a0 += kv.x * kv.x; a1 += kv.y * kv.y;
                a2 += kv.z * kv.z; a3 += kv.w * kv.w;
            }
            snk[g2][r2] = sqrtf((a0 + a1) + (a2 + a3));
        }
        __syncthreads();

        // ---- NF: raw cosine dots (1024) + M row norms (256) ----
        {
            int g = tid >> 9, rm = tid & 511, r = rm >> 7, m = rm & 127;
            float a0 = 0.f, a1 = 0.f, a2 = 0.f, a3 = 0.f;
#pragma unroll
            for (int d4 = 0; d4 < 10; ++d4) {
                float4 kv = *(const float4*)&sk[g][r][d4 * 4];
                float4 mv = *(const float4*)&sM[g][m][d4 * 4];
                a0 += kv.x * mv.x; a1 += kv.y * mv.y;
                a2 += kv.z * mv.z; a3 += kv.w * mv.w;
            }
            sKs[g][r][m] = (a0 + a1) + (a2 + a3);
        }
        if (tid < 256) {
            int g = tid >> 7, m = tid & 127;
            float a0 = 0.f, a1 = 0.f, a2 = 0.f, a3 = 0.f;
#pragma unroll
            for (int d4 = 0; d4 < 10; ++d4) {
                float4 mv = *(const float4*)&sM[g][m][d4 * 4];
                a0 += mv.x * mv.x; a1 += mv.y * mv.y;
                a2 += mv.z * mv.z; a3 += mv.w * mv.w;
            }
            snM[g][m] = sqrtf((a0 + a1) + (a2 + a3));
        }
        __syncthreads();

        // ---- G: cosine normalize + softmax over m -> wr_new (8 waves) ----
        if (w < 8) {
            int g = w >> 2, r = w & 3, ln = l;
            float ink = snk[g][r];
            float a = sKs[g][r][ln] / (ink * snM[g][ln]);
            float b = sKs[g][r][ln + 64] / (ink * snM[g][ln + 64]);
            float mx = fmaxf(a, b);
#pragma unroll
            for (int off = 32; off; off >>= 1) mx = fmaxf(mx, __shfl_xor(mx, off));
            float ea = __expf(a - mx), eb = __expf(b - mx);
            float s = ea + eb;
#pragma unroll
            for (int off = 32; off; off >>= 1) s += __shfl_xor(s, off);
            float inv = 1.f / s;
            swr[g][r][ln]      = ea * inv;
            swr[g][r][ln + 64] = eb * inv;
        }
        __syncthreads();

        // ---- H: read vectors (80, float4) | usage update (256) ----
        if (tid < 80) {
            int g = tid / 40, rd4 = tid % 40, r = rd4 / 10, d4 = rd4 % 10;
            float a0 = 0.f, a1 = 0.f, a2 = 0.f, a3 = 0.f;
            for (int m = 0; m < NMEM; ++m) {
                float wv = swr[g][r][m];
                float4 mv = *(const float4*)&sM[g][m][d4 * 4];
                a0 += wv * mv.x; a1 += wv * mv.y;
                a2 += wv * mv.z; a3 += wv * mv.w;
            }
            float4 res = {a0, a1, a2, a3};
            *(float4*)&sr[g][r * DMEM + d4 * 4] = res;
        } else if (tid >= 640 && tid < 896) {
            int e = tid - 640;
            int g = e >> 7, m = e & 127;
            float wu = GAMMA_ * swu[g][m];
#pragma unroll
            for (int r = 0; r < RH; ++r) wu += swr[g][r][m] + sww[g][r][m];
            swu[g][m] = wu;
        }
        __syncthreads();

        // ---- I1: output head GEMV (320) | kth-smallest + wlu (128) ----
        if (tid < 320) {
            int g = tid / RD, v = tid % RD, o = v >> 5, ln = v & 31;
            const float* wrow = Wo + o * (HDIM + RD);
            float acc = 0.f;
            for (int j = ln; j < HDIM; j += 32) acc += sh[g][j] * wrow[j];
            for (int d = ln; d < RD; d += 32) acc += sr[g][d] * wrow[HDIM + d];
#pragma unroll
            for (int off = 16; off; off >>= 1) acc += __shfl_xor(acc, off, 32);
            if (ln == 0) stmp[g][o] = acc + bo[o];
        } else if (tid >= 640 && tid < 768) {
            int a = tid - 640; int g = a >> 6, ln = a & 63;  // waves 10,11
            float o0 = swu[g][ln], o1 = swu[g][ln + 64];
            float v0 = o0, v1 = o1, kth = 0.f;
#pragma unroll
            for (int it = 0; it < RH; ++it) {
                bool p1 = (v1 < v0);
                float mv = p1 ? v1 : v0;
                int   mi = p1 ? ln + 64 : ln;
                for (int off = 32; off; off >>= 1) {
                    float ov = __shfl_xor(mv, off);
                    int   oi = __shfl_xor(mi, off);
                    if (ov < mv || (ov == mv && oi < mi)) { mv = ov; mi = oi; }
                }
                kth = mv;
                if (mi == ln) v0 = __builtin_inff();
                else if (mi == ln + 64) v1 = __builtin_inff();
            }
            swlu[g][ln]      = (o0 <= kth) ? 1.f : 0.f;
            swlu[g][ln + 64] = (o1 <= kth) ? 1.f : 0.f;
        }
        __syncthreads();

        // ---- I2: final sigmoid+softmax + store (no trailing barrier) ----
        if (tid < NG) {
            int g = tid;
            float v[NWAY], mx = -1e30f;
#pragma unroll
            for (int o = 0; o < NWAY; ++o) { v[o] = sigmoidf_(stmp[g][o]); mx = fmaxf(mx, v[o]); }
            float s = 0.f;
#pragma unroll
            for (int o = 0; o < NWAY; ++o) { v[o] = __expf(v[o] - mx); s += v[o]; }
            float inv = 1.f / s;
            float* op = out + ((size_t)t * BATCH + (b0 + g)) * NWAY;
#pragma unroll
            for (int o = 0; o < NWAY; ++o) op[o] = v[o] * inv;
        }
    }
}

extern "C" void kernel_launch(void* const* d_in, const int* in_sizes, int n_in,
                              void* d_out, int out_size, void* d_ws, size_t ws_size,
                              hipStream_t stream) {
    const float* x    = (const float*)d_in[0];
    const float* W_ih = (const float*)d_in[1];
    const float* W_hh = (const float*)d_in[2];
    const float* b_ih = (const float*)d_in[3];
    const float* b_hh = (const float*)d_in[4];
    const float* Wk   = (const float*)d_in[5];
    const float* bk   = (const float*)d_in[6];
    const float* Wsm  = (const float*)d_in[7];
    const float* bs   = (const float*)d_in[8];
    const float* Wo   = (const float*)d_in[9];
    const float* bo   = (const float*)d_in[10];
    float* out = (float*)d_out;

    const size_t gx_elems  = (size_t)TSTEPS * BATCH * G4H;  // 40,960,000 f32
    const size_t whht_e    = (size_t)HDIM * G4H;            // u16
    const size_t wkt_e     = (size_t)HDIM * RD;             // u16
    const size_t a_elems   = (size_t)TSTEPS * BATCH * KP;   // u16 each
    const size_t w_elems   = (size_t)2 * WROWS * KP;        // u16
    const size_t need_base = gx_elems * 4 + (whht_e + wkt_e) * 2;
    const size_t need_mfma = need_base + (2 * a_elems + w_elems) * 2;
    if (ws_size < need_base) return;

    float* gxb = (float*)d_ws;
    unsigned short* WhhT_bf = (unsigned short*)(gxb + gx_elems);
    unsigned short* WkT_bf  = WhhT_bf + whht_e;

    {
        int tot = (int)(whht_e + wkt_e);
        convert_recT<<<dim3((tot + 255) / 256), dim3(256), 0, stream>>>(W_hh, Wk, WhhT_bf, WkT_bf);
    }

    if (ws_size >= need_mfma) {
        unsigned short* Ahi = WkT_bf + wkt_e;
        unsigned short* Alo = Ahi + a_elems;
        unsigned short* Wpk = Alo + a_elems;
        convert_A<<<dim3(2, TSTEPS * BATCH), dim3(256), 0, stream>>>(x, Ahi, Alo);
        convert_W<<<dim3(2, WROWS, 2), dim3(256), 0, stream>>>(W_ih, Wpk);
        gx_gemm_mfma<<<dim3(7, (TSTEPS * BATCH) / 128), dim3(256), 0, stream>>>(
            Ahi, Alo, Wpk, b_ih, b_hh, gxb);
    } else {
        gx_gemm<<<dim3(G4H / 80, (TSTEPS * BATCH) / 128), dim3(256), 0, stream>>>(
            x, W_ih, b_ih, b_hh, gxb);
    }

    ntm_scan<<<dim3(BATCH / NG), dim3(1024), 0, stream>>>(
        gxb, WhhT_bf, WkT_bf, bk, Wsm, bs, Wo, bo, out);
}

// Round 7
// 1543.574 us; speedup vs baseline: 1.9709x; 1.9709x over previous
//
#include <hip/hip_runtime.h>
#include <stdint.h>

#define TSTEPS 50
#define BATCH  1024
#define INDIM  405
#define KP     448      // padded K for gx GEMM (7 x 64)
#define HDIM   200
#define G4H    800      // 4*H
#define NMEM   128
#define DMEM   40
#define DPAD   44       // sM row stride: 16B-aligned
#define RH     4
#define RD     160      // RH*DMEM
#define NWAY   5
#define GAMMA_ 0.99f
#define NG     2        // batches per block; 512 blocks, 512 thr -> 2 blocks/CU
#define WROWS  928      // gx GEMM W rows padded

typedef __attribute__((ext_vector_type(8))) short short8;
typedef __attribute__((ext_vector_type(4))) float f32x4;

__device__ __forceinline__ float sigmoidf_(float x) {
    return 1.f / (1.f + __expf(-x));
}
__device__ __forceinline__ float ftanh(float x) {
    float e = __expf(2.f * x);
    return 1.f - 2.f / (e + 1.f);
}
__device__ __forceinline__ unsigned short f2bf(float f) {   // RNE f32->bf16
    uint32_t u = __float_as_uint(f);
    uint32_t r = u + 0x7FFFu + ((u >> 16) & 1u);
    return (unsigned short)(r >> 16);
}
__device__ __forceinline__ float bf2f(unsigned short h) {
    return __uint_as_float(((uint32_t)h) << 16);
}

// ---- W_hh -> u32 pair-packed bf16 [200][400]; Wk -> bf16 [200][160] -------
__global__ __launch_bounds__(256) void convert_recT(const float* __restrict__ W_hh,
                                                    const float* __restrict__ Wk,
                                                    uint32_t* __restrict__ Whh_pk,
                                                    unsigned short* __restrict__ WkT_bf) {
    int i = blockIdx.x * 256 + threadIdx.x;
    if (i < HDIM * 400) {
        int j = i / 400, p = i % 400;
        uint32_t lo = f2bf(W_hh[(2 * p)     * HDIM + j]);
        uint32_t hi = f2bf(W_hh[(2 * p + 1) * HDIM + j]);
        Whh_pk[i] = (hi << 16) | lo;
    } else if (i < HDIM * 400 + HDIM * RD) {
        int e = i - HDIM * 400;
        int j = e / RD, rd = e % RD;
        WkT_bf[e] = f2bf(Wk[rd * HDIM + j]);
    }
}

// ---------------- split f32 -> (hi, lo) bf16, zero-padded K (gx GEMM) ------
__global__ __launch_bounds__(256) void convert_A(const float* __restrict__ x,
                                                 unsigned short* __restrict__ Ahi,
                                                 unsigned short* __restrict__ Alo) {
    int c = blockIdx.x * 256 + threadIdx.x;
    int r = blockIdx.y;
    if (c >= KP) return;
    float v = (c < INDIM) ? x[(size_t)r * INDIM + c] : 0.f;
    unsigned short hi = f2bf(v);
    unsigned short lo = f2bf(v - bf2f(hi));
    size_t o = (size_t)r * KP + c;
    Ahi[o] = hi;
    Alo[o] = lo;
}

__global__ __launch_bounds__(256) void convert_W(const float* __restrict__ W_ih,
                                                 unsigned short* __restrict__ Wpk) {
    int c = blockIdx.x * 256 + threadIdx.x;
    int n = blockIdx.y;
    int sec = blockIdx.z;
    if (c >= KP) return;
    float v = (n < G4H && c < INDIM) ? W_ih[(size_t)n * INDIM + c] : 0.f;
    unsigned short hi = f2bf(v);
    size_t o = (size_t)sec * WROWS * KP + (size_t)n * KP + c;
    Wpk[o] = (sec == 0) ? hi : f2bf(v - bf2f(hi));
}

// ---------------- gx GEMM via 3-term split-bf16 MFMA ----------------------
__global__ __launch_bounds__(256) void gx_gemm_mfma(
        const unsigned short* __restrict__ Ahi,
        const unsigned short* __restrict__ Alo,
        const unsigned short* __restrict__ Wpk,
        const float* __restrict__ b_ih, const float* __restrict__ b_hh,
        float* __restrict__ gx) {
    __shared__ unsigned short Alds[128 * 64];
    __shared__ unsigned short Blds[128 * 64];
    const int tid = threadIdx.x;
    const int wv = tid >> 6, ln = tid & 63;
    const int wr = wv >> 1, wc = wv & 1;
    const int n0 = blockIdx.x * 128;
    const int m0 = blockIdx.y * 128;

    f32x4 acc[4][4];
#pragma unroll
    for (int m = 0; m < 4; ++m)
#pragma unroll
        for (int n = 0; n < 4; ++n) acc[m][n] = (f32x4){0.f, 0.f, 0.f, 0.f};

    int erow[4], ecol[4];
#pragma unroll
    for (int i = 0; i < 4; ++i) {
        int e = (i * 4 + wv) * 512 + ln * 8;
        erow[i] = e >> 6;
        ecol[i] = e & 63;
    }

    const unsigned short* Whi = Wpk;
    const unsigned short* Wlo = Wpk + (size_t)WROWS * KP;

#pragma unroll 1
    for (int s = 0; s < 3; ++s) {
        const unsigned short* Ab = ((s == 2) ? Alo : Ahi) + (size_t)m0 * KP;
        const unsigned short* Bb = ((s == 1) ? Wlo : Whi) + (size_t)n0 * KP;

        short8 ar[4], br[4];
#pragma unroll
        for (int i = 0; i < 4; ++i) {
            ar[i] = *(const short8*)&Ab[(size_t)erow[i] * KP + ecol[i]];
            br[i] = *(const short8*)&Bb[(size_t)erow[i] * KP + ecol[i]];
        }

#pragma unroll 1
        for (int k0 = 0; k0 < KP; k0 += 64) {
            __syncthreads();
#pragma unroll
            for (int i = 0; i < 4; ++i) {
                int e = (i * 4 + wv) * 512 + ln * 8;
                *(short8*)&Alds[e] = ar[i];
                *(short8*)&Blds[e] = br[i];
            }
            __syncthreads();
            if (k0 + 64 < KP) {
#pragma unroll
                for (int i = 0; i < 4; ++i) {
                    ar[i] = *(const short8*)&Ab[(size_t)erow[i] * KP + k0 + 64 + ecol[i]];
                    br[i] = *(const short8*)&Bb[(size_t)erow[i] * KP + k0 + 64 + ecol[i]];
                }
            }
#pragma unroll
            for (int ks = 0; ks < 2; ++ks) {
                short8 af[4], bf[4];
                int kcol = ks * 32 + (ln >> 4) * 8;
#pragma unroll
                for (int m = 0; m < 4; ++m) {
                    int row = wr * 64 + m * 16 + (ln & 15);
                    af[m] = *(const short8*)&Alds[row * 64 + kcol];
                }
#pragma unroll
                for (int n = 0; n < 4; ++n) {
                    int row = wc * 64 + n * 16 + (ln & 15);
                    bf[n] = *(const short8*)&Blds[row * 64 + kcol];
                }
#pragma unroll
                for (int m = 0; m < 4; ++m)
#pragma unroll
                    for (int n = 0; n < 4; ++n)
                        acc[m][n] = __builtin_amdgcn_mfma_f32_16x16x32_bf16(
                            af[m], bf[n], acc[m][n], 0, 0, 0);
            }
        }
    }

#pragma unroll
    for (int n = 0; n < 4; ++n) {
        int col = n0 + wc * 64 + n * 16 + (ln & 15);
        if (col >= G4H) continue;
        float bias = b_ih[col] + b_hh[col];
#pragma unroll
        for (int m = 0; m < 4; ++m) {
#pragma unroll
            for (int j = 0; j < 4; ++j) {
                int row = m0 + wr * 64 + m * 16 + (ln >> 4) * 4 + j;
                gx[(size_t)row * G4H + col] = acc[m][n][j] + bias;
            }
        }
    }
}

// ---------------- f32 fallback GEMM ---------------------------------------
__global__ __launch_bounds__(256) void gx_gemm(const float* __restrict__ x,
                                               const float* __restrict__ W_ih,
                                               const float* __restrict__ b_ih,
                                               const float* __restrict__ b_hh,
                                               float* __restrict__ gx) {
    const int BM = 128, BN = 80, BK = 16;
    __shared__ float As[BK][BM];
    __shared__ float Bs[BK][BN];
    int m0 = blockIdx.y * BM;
    int n0 = blockIdx.x * BN;
    int tid = threadIdx.x;
    int tm = tid >> 4, tn = tid & 15;
    float acc[8][5];
#pragma unroll
    for (int i = 0; i < 8; ++i)
#pragma unroll
        for (int j = 0; j < 5; ++j) acc[i][j] = 0.f;

    for (int k0 = 0; k0 < INDIM; k0 += BK) {
        {
            int row = tid >> 1, kk = (tid & 1) * 8;
            const float* ap = x + (size_t)(m0 + row) * INDIM + k0 + kk;
#pragma unroll
            for (int i = 0; i < 8; ++i)
                As[kk + i][row] = (k0 + kk + i < INDIM) ? ap[i] : 0.f;
        }
        if (tid < 160) {
            int col = tid >> 1, kk = (tid & 1) * 8;
            const float* bp = W_ih + (size_t)(n0 + col) * INDIM + k0 + kk;
#pragma unroll
            for (int i = 0; i < 8; ++i)
                Bs[kk + i][col] = (k0 + kk + i < INDIM) ? bp[i] : 0.f;
        }
        __syncthreads();
#pragma unroll
        for (int k = 0; k < BK; ++k) {
            float a[8], b[5];
#pragma unroll
            for (int i = 0; i < 8; ++i) a[i] = As[k][tm * 8 + i];
#pragma unroll
            for (int j = 0; j < 5; ++j) b[j] = Bs[k][tn * 5 + j];
#pragma unroll
            for (int i = 0; i < 8; ++i)
#pragma unroll
                for (int j = 0; j < 5; ++j) acc[i][j] += a[i] * b[j];
        }
        __syncthreads();
    }
#pragma unroll
    for (int j = 0; j < 5; ++j) {
        int n = n0 + tn * 5 + j;
        float bias = b_ih[n] + b_hh[n];
#pragma unroll
        for (int i = 0; i < 8; ++i) {
            int m = m0 + tm * 8 + i;
            gx[(size_t)m * G4H + n] = acc[i][j] + bias;
        }
    }
}

// ---------------- persistent NTM scan: NG=2, 512 thr, 2 blocks/CU ----------
__global__ __launch_bounds__(512, 4) void ntm_scan(
        const float* __restrict__ gx,            // [T][B][800]
        const uint32_t* __restrict__ Whh_pk,     // [200][400] u32 bf16-pairs
        const unsigned short* __restrict__ WkT_bf, // [200][160] bf16
        const float* __restrict__ bk,
        const float* __restrict__ Wsm,           // [4][200]
        const float* __restrict__ bs,
        const float* __restrict__ Wo,            // [5][360]
        const float* __restrict__ bo,
        float* __restrict__ out) {               // [T][B][5]
    __shared__ float sM[NG][NMEM][DPAD];   // 45 KB
    __shared__ float sh[NG][HDIM];
    __shared__ float sgate[NG][G4H];       // raw recurrent gates (o-major)
    __shared__ float spartK[NG][2][RD];
    __shared__ float spartS[NG][RH][4];
    __shared__ float swr[NG][RH][NMEM];
    __shared__ float sww[NG][RH][NMEM];
    __shared__ float sKs[NG][RH][NMEM];
    __shared__ float swu[NG][NMEM];
    __shared__ float swlu[NG][NMEM];
    __shared__ float sk[NG][RH][DMEM];
    __shared__ float sr[NG][RD];
    __shared__ float snk[NG][RH];
    __shared__ float ssig[NG][RH];
    __shared__ float snM[NG][NMEM];
    __shared__ float stmp[NG][NWAY];
    __shared__ int   sidx[NG];

    const int tid = threadIdx.x;
    const int b0  = blockIdx.x * NG;
    const int w   = tid >> 6, l = tid & 63;

    // ---- init carries ----
    for (int e = tid; e < NG * NMEM * DPAD; e += 512) ((float*)sM)[e] = 0.f;
    for (int e = tid; e < NG * HDIM; e += 512) ((float*)sh)[e] = 0.f;
    for (int e = tid; e < NG * RH * NMEM; e += 512) ((float*)swr)[e] = 0.f;
    for (int e = tid; e < NG * NMEM; e += 512) { ((float*)swu)[e] = 0.f; ((float*)swlu)[e] = 1.f; }

    // B-phase thread state: tid<400 owns (g=tid/200, j=tid%200)
    float c_reg = 0.f;
    float gxr0 = 0.f, gxr1 = 0.f, gxr2 = 0.f, gxr3 = 0.f;
    int pg = 0, pj = 0;
    if (tid < NG * HDIM) {
        pg = tid / HDIM; pj = tid - pg * HDIM;
        const float* gxp = gx + (size_t)(b0 + pg) * G4H + pj;
        gxr0 = gxp[0]; gxr1 = gxp[HDIM]; gxr2 = gxp[2 * HDIM]; gxr3 = gxp[3 * HDIM];
    }
    __syncthreads();

    for (int t = 0; t < TSTEPS; ++t) {
        // ---- A: raw gates = h @ WhhT (400 thr, 2 outputs x 2 batches each) ----
        if (tid < 400) {
            const int p = tid;
            float a00 = 0.f, a01 = 0.f, a10 = 0.f, a11 = 0.f;
#pragma unroll 2
            for (int j = 0; j < HDIM; j += 4) {
                float4 h0 = *(const float4*)&sh[0][j];
                float4 h1 = *(const float4*)&sh[1][j];
                uint32_t b0w = Whh_pk[(j + 0) * 400 + p];
                uint32_t b1w = Whh_pk[(j + 1) * 400 + p];
                uint32_t b2w = Whh_pk[(j + 2) * 400 + p];
                uint32_t b3w = Whh_pk[(j + 3) * 400 + p];
                float we0 = __uint_as_float(b0w << 16), wo0 = __uint_as_float(b0w & 0xFFFF0000u);
                float we1 = __uint_as_float(b1w << 16), wo1 = __uint_as_float(b1w & 0xFFFF0000u);
                float we2 = __uint_as_float(b2w << 16), wo2 = __uint_as_float(b2w & 0xFFFF0000u);
                float we3 = __uint_as_float(b3w << 16), wo3 = __uint_as_float(b3w & 0xFFFF0000u);
                a00 += we0 * h0.x + we1 * h0.y + we2 * h0.z + we3 * h0.w;
                a01 += wo0 * h0.x + wo1 * h0.y + wo2 * h0.z + wo3 * h0.w;
                a10 += we0 * h1.x + we1 * h1.y + we2 * h1.z + we3 * h1.w;
                a11 += wo0 * h1.x + wo1 * h1.y + wo2 * h1.z + wo3 * h1.w;
            }
            sgate[0][2 * p]     = a00;
            sgate[0][2 * p + 1] = a01;
            sgate[1][2 * p]     = a10;
            sgate[1][2 * p + 1] = a11;
        }
        __syncthreads();

        // ---- B: LSTM cell (400 thr); c in regs; prefetch next gx ----
        if (tid < NG * HDIM) {
            float ig = sigmoidf_(sgate[pg][pj] + gxr0);
            float fg = sigmoidf_(sgate[pg][pj + HDIM] + gxr1);
            float gv = ftanh(sgate[pg][pj + 2 * HDIM] + gxr2);
            float og = sigmoidf_(sgate[pg][pj + 3 * HDIM] + gxr3);
            c_reg = fg * c_reg + ig * gv;
            sh[pg][pj] = og * ftanh(c_reg);
            if (t + 1 < TSTEPS) {
                const float* gxp = gx + ((size_t)(t + 1) * BATCH + b0 + pg) * G4H + pj;
                gxr0 = gxp[0]; gxr1 = gxp[HDIM]; gxr2 = gxp[2 * HDIM]; gxr3 = gxp[3 * HDIM];
            }
        }
        __syncthreads();

        // ---- C: key partials (320) | argmin wu (128) | sigma partials (32) ----
        if (tid < 320) {
            int col = tid % RD, c = tid / RD;   // 2 K-chunks of 100
            int jb = c * 100;
            const unsigned short* wp = WkT_bf + col;
            float a0 = 0.f, a1 = 0.f;
#pragma unroll 2
            for (int j = jb; j < jb + 100; j += 4) {
                float4 h0 = *(const float4*)&sh[0][j];
                float4 h1 = *(const float4*)&sh[1][j];
                float w0 = bf2f(wp[(j + 0) * RD]);
                float w1 = bf2f(wp[(j + 1) * RD]);
                float w2 = bf2f(wp[(j + 2) * RD]);
                float w3 = bf2f(wp[(j + 3) * RD]);
                a0 += w0 * h0.x + w1 * h0.y + w2 * h0.z + w3 * h0.w;
                a1 += w0 * h1.x + w1 * h1.y + w2 * h1.z + w3 * h1.w;
            }
            spartK[0][c][col] = a0;
            spartK[1][c][col] = a1;
        } else if (tid < 448) {
            int a = tid - 320; int g = a >> 6, ln = a & 63;   // waves 5,6
            float v0 = swu[g][ln], v1 = swu[g][ln + 64];
            bool p1 = (v1 < v0);
            float mv = p1 ? v1 : v0;
            int   mi = p1 ? ln + 64 : ln;
#pragma unroll
            for (int off = 32; off; off >>= 1) {
                float ov = __shfl_xor(mv, off);
                int   oi = __shfl_xor(mi, off);
                if (ov < mv || (ov == mv && oi < mi)) { mv = ov; mi = oi; }
            }
            if (ln == 0) sidx[g] = mi;
        } else if (tid < 480) {
            int v = tid - 448; int g = v >> 4, rc = v & 15, r = rc >> 2, cc = rc & 3;
            const float* wrow = Wsm + r * HDIM;
            float a = 0.f;
            for (int j = 50 * cc; j < 50 * cc + 50; ++j) a += sh[g][j] * wrow[j];
            spartS[g][r][cc] = a;
        }
        __syncthreads();

        // ---- D: finalize k (320) | finalize sigma (8) ----
        if (tid < 320) {
            int g = tid / RD, col = tid % RD;
            float s = spartK[g][0][col] + spartK[g][1][col] + bk[col];
            sk[g][col / DMEM][col % DMEM] = ftanh(s);
        } else if (tid < 328) {
            int v = tid - 320; int g = v >> 2, r = v & 3;
            float s = spartS[g][r][0] + spartS[g][r][1]
                    + spartS[g][r][2] + spartS[g][r][3] + bs[r];
            ssig[g][r] = sigmoidf_(ftanh(s));
        }
        __syncthreads();

        // ---- E2': ww + zero-LU-row + rank-4 M update (512) ; ||k|| (8) ----
        {
            int g = tid >> 8, mh = tid & 255, m = mh >> 1, dh = mh & 1;
            float sg0 = ssig[g][0], sg1 = ssig[g][1], sg2 = ssig[g][2], sg3 = ssig[g][3];
            float wl = swlu[g][m];
            float w0 = sg0 * swr[g][0][m] + (1.f - sg0) * wl;
            float w1 = sg1 * swr[g][1][m] + (1.f - sg1) * wl;
            float w2 = sg2 * swr[g][2][m] + (1.f - sg2) * wl;
            float w3 = sg3 * swr[g][3][m] + (1.f - sg3) * wl;
            if (!dh) {
                sww[g][0][m] = w0; sww[g][1][m] = w1;
                sww[g][2][m] = w2; sww[g][3][m] = w3;
            }
            bool zr = (m == sidx[g]);
            int d0 = dh * 20;
#pragma unroll
            for (int q = 0; q < 5; ++q) {
                int d = d0 + q * 4;
                float4 mv = *(const float4*)&sM[g][m][d];
                float4 k0 = *(const float4*)&sk[g][0][d];
                float4 k1 = *(const float4*)&sk[g][1][d];
                float4 k2 = *(const float4*)&sk[g][2][d];
                float4 k3 = *(const float4*)&sk[g][3][d];
                float4 o;
                o.x = (zr ? 0.f : mv.x) + w0 * k0.x + w1 * k1.x + w2 * k2.x + w3 * k3.x;
                o.y = (zr ? 0.f : mv.y) + w0 * k0.y + w1 * k1.y + w2 * k2.y + w3 * k3.y;
                o.z = (zr ? 0.f : mv.z) + w0 * k0.z + w1 * k1.z + w2 * k2.z + w3 * k3.z;
                o.w = (zr ? 0.f : mv.w) + w0 * k0.w + w1 * k1.w + w2 * k2.w + w3 * k3.w;
                *(float4*)&sM[g][m][d] = o;
            }
            if (tid < 8) {
                int g2 = tid >> 2, r2 = tid & 3;
                float a0 = 0.f, a1 = 0.f, a2 = 0.f, a3 = 0.f;
#pragma unroll
                for (int q = 0; q < 10; ++q) {
                    float4 kv = *(const float4*)&sk[g2][r2][q * 4];
                    a0 += kv.x * kv.x; a1 += kv.y * kv.y;
                    a2 += kv.z * kv.z; a3 += kv.w * kv.w;
                }
                snk[g2][r2] = sqrtf((a0 + a1) + (a2 + a3));
            }
        }
        __syncthreads();

        // ---- NF: raw cosine dots (2x512) + M row norms (256) ----
#pragma unroll
        for (int q = 0; q < 2; ++q) {
            int e = tid + q * 512;
            int g = e >> 9, rm = e & 511, r = rm >> 7, m = rm & 127;
            float a0 = 0.f, a1 = 0.f, a2 = 0.f, a3 = 0.f;
#pragma unroll
            for (int d4 = 0; d4 < 10; ++d4) {
                float4 kv = *(const float4*)&sk[g][r][d4 * 4];
                float4 mv = *(const float4*)&sM[g][m][d4 * 4];
                a0 += kv.x * mv.x; a1 += kv.y * mv.y;
                a2 += kv.z * mv.z; a3 += kv.w * mv.w;
            }
            sKs[g][r][m] = (a0 + a1) + (a2 + a3);
        }
        if (tid < 256) {
            int g = tid >> 7, m = tid & 127;
            float a0 = 0.f, a1 = 0.f, a2 = 0.f, a3 = 0.f;
#pragma unroll
            for (int d4 = 0; d4 < 10; ++d4) {
                float4 mv = *(const float4*)&sM[g][m][d4 * 4];
                a0 += mv.x * mv.x; a1 += mv.y * mv.y;
                a2 += mv.z * mv.z; a3 += mv.w * mv.w;
            }
            snM[g][m] = sqrtf((a0 + a1) + (a2 + a3));
        }
        __syncthreads();

        // ---- G: cosine normalize + softmax over m -> wr_new (8 waves) ----
        {
            int g = w >> 2, r = w & 3, ln = l;
            float ink = snk[g][r];
            float a = sKs[g][r][ln] / (ink * snM[g][ln]);
            float b = sKs[g][r][ln + 64] / (ink * snM[g][ln + 64]);
            float mx = fmaxf(a, b);
#pragma unroll
            for (int off = 32; off; off >>= 1) mx = fmaxf(mx, __shfl_xor(mx, off));
            float ea = __expf(a - mx), eb = __expf(b - mx);
            float s = ea + eb;
#pragma unroll
            for (int off = 32; off; off >>= 1) s += __shfl_xor(s, off);
            float inv = 1.f / s;
            swr[g][r][ln]      = ea * inv;
            swr[g][r][ln + 64] = eb * inv;
        }
        __syncthreads();

        // ---- H: read vectors (80, float4) | usage update (256) ----
        if (tid < 80) {
            int g = tid / 40, rd4 = tid % 40, r = rd4 / 10, d4 = rd4 % 10;
            float a0 = 0.f, a1 = 0.f, a2 = 0.f, a3 = 0.f;
            for (int m = 0; m < NMEM; ++m) {
                float wv = swr[g][r][m];
                float4 mv = *(const float4*)&sM[g][m][d4 * 4];
                a0 += wv * mv.x; a1 += wv * mv.y;
                a2 += wv * mv.z; a3 += wv * mv.w;
            }
            float4 res = {a0, a1, a2, a3};
            *(float4*)&sr[g][r * DMEM + d4 * 4] = res;
        } else if (tid >= 256) {
            int e = tid - 256;
            int g = e >> 7, m = e & 127;
            float wu = GAMMA_ * swu[g][m];
#pragma unroll
            for (int r = 0; r < RH; ++r) wu += swr[g][r][m] + sww[g][r][m];
            swu[g][m] = wu;
        }
        __syncthreads();

        // ---- I1: output head GEMV (320) | kth-smallest + wlu (128) ----
        if (tid < 320) {
            int g = tid / RD, v = tid % RD, o = v >> 5, ln = v & 31;
            const float* wrow = Wo + o * (HDIM + RD);
            float acc = 0.f;
            for (int j = ln; j < HDIM; j += 32) acc += sh[g][j] * wrow[j];
            for (int d = ln; d < RD; d += 32) acc += sr[g][d] * wrow[HDIM + d];
#pragma unroll
            for (int off = 16; off; off >>= 1) acc += __shfl_xor(acc, off, 32);
            if (ln == 0) stmp[g][o] = acc + bo[o];
        } else if (tid < 448) {
            int a = tid - 320; int g = a >> 6, ln = a & 63;   // waves 5,6
            float o0 = swu[g][ln], o1 = swu[g][ln + 64];
            float v0 = o0, v1 = o1, kth = 0.f;
#pragma unroll
            for (int it = 0; it < RH; ++it) {
                bool p1 = (v1 < v0);
                float mv = p1 ? v1 : v0;
                int   mi = p1 ? ln + 64 : ln;
                for (int off = 32; off; off >>= 1) {
                    float ov = __shfl_xor(mv, off);
                    int   oi = __shfl_xor(mi, off);
                    if (ov < mv || (ov == mv && oi < mi)) { mv = ov; mi = oi; }
                }
                kth = mv;
                if (mi == ln) v0 = __builtin_inff();
                else if (mi == ln + 64) v1 = __builtin_inff();
            }
            swlu[g][ln]      = (o0 <= kth) ? 1.f : 0.f;
            swlu[g][ln + 64] = (o1 <= kth) ? 1.f : 0.f;
        }
        __syncthreads();

        // ---- I2: final sigmoid+softmax + store (no trailing barrier) ----
        if (tid < NG) {
            int g = tid;
            float v[NWAY], mx = -1e30f;
#pragma unroll
            for (int o = 0; o < NWAY; ++o) { v[o] = sigmoidf_(stmp[g][o]); mx = fmaxf(mx, v[o]); }
            float s = 0.f;
#pragma unroll
            for (int o = 0; o < NWAY; ++o) { v[o] = __expf(v[o] - mx); s += v[o]; }
            float inv = 1.f / s;
            float* op = out + ((size_t)t * BATCH + (b0 + g)) * NWAY;
#pragma unroll
            for (int o = 0; o < NWAY; ++o) op[o] = v[o] * inv;
        }
    }
}

extern "C" void kernel_launch(void* const* d_in, const int* in_sizes, int n_in,
                              void* d_out, int out_size, void* d_ws, size_t ws_size,
                              hipStream_t stream) {
    const float* x    = (const float*)d_in[0];
    const float* W_ih = (const float*)d_in[1];
    const float* W_hh = (const float*)d_in[2];
    const float* b_ih = (const float*)d_in[3];
    const float* b_hh = (const float*)d_in[4];
    const float* Wk   = (const float*)d_in[5];
    const float* bk   = (const float*)d_in[6];
    const float* Wsm  = (const float*)d_in[7];
    const float* bs   = (const float*)d_in[8];
    const float* Wo   = (const float*)d_in[9];
    const float* bo   = (const float*)d_in[10];
    float* out = (float*)d_out;

    const size_t gx_elems  = (size_t)TSTEPS * BATCH * G4H;  // 40,960,000 f32
    const size_t whh_u32   = (size_t)HDIM * 400;            // u32
    const size_t wkt_e     = (size_t)HDIM * RD;             // u16
    const size_t a_elems   = (size_t)TSTEPS * BATCH * KP;   // u16 each
    const size_t w_elems   = (size_t)2 * WROWS * KP;        // u16
    const size_t need_base = gx_elems * 4 + whh_u32 * 4 + wkt_e * 2;
    const size_t need_mfma = need_base + (2 * a_elems + w_elems) * 2;
    if (ws_size < need_base) return;

    float* gxb = (float*)d_ws;
    uint32_t* Whh_pk = (uint32_t*)(gxb + gx_elems);
    unsigned short* WkT_bf = (unsigned short*)(Whh_pk + whh_u32);

    {
        int tot = (int)(whh_u32 + wkt_e);
        convert_recT<<<dim3((tot + 255) / 256), dim3(256), 0, stream>>>(W_hh, Wk, Whh_pk, WkT_bf);
    }

    if (ws_size >= need_mfma) {
        unsigned short* Ahi = WkT_bf + wkt_e;
        unsigned short* Alo = Ahi + a_elems;
        unsigned short* Wpk = Alo + a_elems;
        convert_A<<<dim3(2, TSTEPS * BATCH), dim3(256), 0, stream>>>(x, Ahi, Alo);
        convert_W<<<dim3(2, WROWS, 2), dim3(256), 0, stream>>>(W_ih, Wpk);
        gx_gemm_mfma<<<dim3(7, (TSTEPS * BATCH) / 128), dim3(256), 0, stream>>>(
            Ahi, Alo, Wpk, b_ih, b_hh, gxb);
    } else {
        gx_gemm<<<dim3(G4H / 80, (TSTEPS * BATCH) / 128), dim3(256), 0, stream>>>(
            x, W_ih, b_ih, b_hh, gxb);
    }

    ntm_scan<<<dim3(BATCH / NG), dim3(512), 0, stream>>>(
        gxb, Whh_pk, WkT_bf, bk, Wsm, bs, Wo, bo, out);
}

// Round 8
// 1539.104 us; speedup vs baseline: 1.9766x; 1.0029x over previous
//
#include <hip/hip_runtime.h>
#include <stdint.h>

#define TSTEPS 50
#define BATCH  1024
#define INDIM  405
#define KP     448      // padded K for gx GEMM (7 x 64)
#define HDIM   200
#define G4H    800      // 4*H
#define NMEM   128
#define DMEM   40
#define DPAD   44       // sM row stride: 16B-aligned
#define RH     4
#define RD     160      // RH*DMEM
#define NWAY   5
#define GAMMA_ 0.99f
#define NG     2        // batches per block; 512 blocks, 512 thr -> 2 blocks/CU
#define WROWS  928      // gx GEMM W rows padded

typedef __attribute__((ext_vector_type(8))) short short8;
typedef __attribute__((ext_vector_type(4))) float f32x4;

__device__ __forceinline__ float sigmoidf_(float x) {
    return 1.f / (1.f + __expf(-x));
}
__device__ __forceinline__ float ftanh(float x) {
    float e = __expf(2.f * x);
    return 1.f - 2.f / (e + 1.f);
}
__device__ __forceinline__ unsigned short f2bf(float f) {   // RNE f32->bf16
    uint32_t u = __float_as_uint(f);
    uint32_t r = u + 0x7FFFu + ((u >> 16) & 1u);
    return (unsigned short)(r >> 16);
}
__device__ __forceinline__ float bf2f(unsigned short h) {
    return __uint_as_float(((uint32_t)h) << 16);
}
__device__ __forceinline__ float bflo(uint32_t u) { return __uint_as_float(u << 16); }
__device__ __forceinline__ float bfhi(uint32_t u) { return __uint_as_float(u & 0xFFFF0000u); }

// ---- quad-pack recurrent weights -------------------------------------------
// Whh_q4[jq*400+p] = {pack(W[2p][4jq],W[2p][4jq+1]), pack(W[2p+1][...]),
//                     pack(W[2p][4jq+2],W[2p][4jq+3]), pack(W[2p+1][...])}
// Wk_q2[jq*160+col] = {pack(Wk[col][4jq],Wk[col][4jq+1]), pack(...+2,+3)}
__global__ __launch_bounds__(256) void convert_recQ(const float* __restrict__ W_hh,
                                                    const float* __restrict__ Wk,
                                                    uint4* __restrict__ Whh_q4,
                                                    uint2* __restrict__ Wk_q2) {
    int i = blockIdx.x * 256 + threadIdx.x;
    if (i < 50 * 400) {
        int jq = i / 400, p = i % 400;
        int j = jq * 4;
        const float* r0 = W_hh + (2 * p) * HDIM;
        const float* r1 = W_hh + (2 * p + 1) * HDIM;
        uint4 v;
        v.x = (uint32_t)f2bf(r0[j])     | ((uint32_t)f2bf(r0[j + 1]) << 16);
        v.y = (uint32_t)f2bf(r1[j])     | ((uint32_t)f2bf(r1[j + 1]) << 16);
        v.z = (uint32_t)f2bf(r0[j + 2]) | ((uint32_t)f2bf(r0[j + 3]) << 16);
        v.w = (uint32_t)f2bf(r1[j + 2]) | ((uint32_t)f2bf(r1[j + 3]) << 16);
        Whh_q4[i] = v;
    } else if (i < 50 * 400 + 50 * 160) {
        int e = i - 50 * 400;
        int jq = e / 160, col = e % 160;
        int j = jq * 4;
        const float* r = Wk + col * HDIM;
        uint2 v;
        v.x = (uint32_t)f2bf(r[j])     | ((uint32_t)f2bf(r[j + 1]) << 16);
        v.y = (uint32_t)f2bf(r[j + 2]) | ((uint32_t)f2bf(r[j + 3]) << 16);
        Wk_q2[e] = v;
    }
}

// ---------------- split f32 -> (hi, lo) bf16, zero-padded K (gx GEMM) ------
__global__ __launch_bounds__(256) void convert_A(const float* __restrict__ x,
                                                 unsigned short* __restrict__ Ahi,
                                                 unsigned short* __restrict__ Alo) {
    int c = blockIdx.x * 256 + threadIdx.x;
    int r = blockIdx.y;
    if (c >= KP) return;
    float v = (c < INDIM) ? x[(size_t)r * INDIM + c] : 0.f;
    unsigned short hi = f2bf(v);
    unsigned short lo = f2bf(v - bf2f(hi));
    size_t o = (size_t)r * KP + c;
    Ahi[o] = hi;
    Alo[o] = lo;
}

__global__ __launch_bounds__(256) void convert_W(const float* __restrict__ W_ih,
                                                 unsigned short* __restrict__ Wpk) {
    int c = blockIdx.x * 256 + threadIdx.x;
    int n = blockIdx.y;
    int sec = blockIdx.z;
    if (c >= KP) return;
    float v = (n < G4H && c < INDIM) ? W_ih[(size_t)n * INDIM + c] : 0.f;
    unsigned short hi = f2bf(v);
    size_t o = (size_t)sec * WROWS * KP + (size_t)n * KP + c;
    Wpk[o] = (sec == 0) ? hi : f2bf(v - bf2f(hi));
}

// ---------------- gx GEMM via 3-term split-bf16 MFMA ----------------------
__global__ __launch_bounds__(256) void gx_gemm_mfma(
        const unsigned short* __restrict__ Ahi,
        const unsigned short* __restrict__ Alo,
        const unsigned short* __restrict__ Wpk,
        const float* __restrict__ b_ih, const float* __restrict__ b_hh,
        float* __restrict__ gx) {
    __shared__ unsigned short Alds[128 * 64];
    __shared__ unsigned short Blds[128 * 64];
    const int tid = threadIdx.x;
    const int wv = tid >> 6, ln = tid & 63;
    const int wr = wv >> 1, wc = wv & 1;
    const int n0 = blockIdx.x * 128;
    const int m0 = blockIdx.y * 128;

    f32x4 acc[4][4];
#pragma unroll
    for (int m = 0; m < 4; ++m)
#pragma unroll
        for (int n = 0; n < 4; ++n) acc[m][n] = (f32x4){0.f, 0.f, 0.f, 0.f};

    int erow[4], ecol[4];
#pragma unroll
    for (int i = 0; i < 4; ++i) {
        int e = (i * 4 + wv) * 512 + ln * 8;
        erow[i] = e >> 6;
        ecol[i] = e & 63;
    }

    const unsigned short* Whi = Wpk;
    const unsigned short* Wlo = Wpk + (size_t)WROWS * KP;

#pragma unroll 1
    for (int s = 0; s < 3; ++s) {
        const unsigned short* Ab = ((s == 2) ? Alo : Ahi) + (size_t)m0 * KP;
        const unsigned short* Bb = ((s == 1) ? Wlo : Whi) + (size_t)n0 * KP;

        short8 ar[4], br[4];
#pragma unroll
        for (int i = 0; i < 4; ++i) {
            ar[i] = *(const short8*)&Ab[(size_t)erow[i] * KP + ecol[i]];
            br[i] = *(const short8*)&Bb[(size_t)erow[i] * KP + ecol[i]];
        }

#pragma unroll 1
        for (int k0 = 0; k0 < KP; k0 += 64) {
            __syncthreads();
#pragma unroll
            for (int i = 0; i < 4; ++i) {
                int e = (i * 4 + wv) * 512 + ln * 8;
                *(short8*)&Alds[e] = ar[i];
                *(short8*)&Blds[e] = br[i];
            }
            __syncthreads();
            if (k0 + 64 < KP) {
#pragma unroll
                for (int i = 0; i < 4; ++i) {
                    ar[i] = *(const short8*)&Ab[(size_t)erow[i] * KP + k0 + 64 + ecol[i]];
                    br[i] = *(const short8*)&Bb[(size_t)erow[i] * KP + k0 + 64 + ecol[i]];
                }
            }
#pragma unroll
            for (int ks = 0; ks < 2; ++ks) {
                short8 af[4], bf[4];
                int kcol = ks * 32 + (ln >> 4) * 8;
#pragma unroll
                for (int m = 0; m < 4; ++m) {
                    int row = wr * 64 + m * 16 + (ln & 15);
                    af[m] = *(const short8*)&Alds[row * 64 + kcol];
                }
#pragma unroll
                for (int n = 0; n < 4; ++n) {
                    int row = wc * 64 + n * 16 + (ln & 15);
                    bf[n] = *(const short8*)&Blds[row * 64 + kcol];
                }
#pragma unroll
                for (int m = 0; m < 4; ++m)
#pragma unroll
                    for (int n = 0; n < 4; ++n)
                        acc[m][n] = __builtin_amdgcn_mfma_f32_16x16x32_bf16(
                            af[m], bf[n], acc[m][n], 0, 0, 0);
            }
        }
    }

#pragma unroll
    for (int n = 0; n < 4; ++n) {
        int col = n0 + wc * 64 + n * 16 + (ln & 15);
        if (col >= G4H) continue;
        float bias = b_ih[col] + b_hh[col];
#pragma unroll
        for (int m = 0; m < 4; ++m) {
#pragma unroll
            for (int j = 0; j < 4; ++j) {
                int row = m0 + wr * 64 + m * 16 + (ln >> 4) * 4 + j;
                gx[(size_t)row * G4H + col] = acc[m][n][j] + bias;
            }
        }
    }
}

// ---------------- f32 fallback GEMM ---------------------------------------
__global__ __launch_bounds__(256) void gx_gemm(const float* __restrict__ x,
                                               const float* __restrict__ W_ih,
                                               const float* __restrict__ b_ih,
                                               const float* __restrict__ b_hh,
                                               float* __restrict__ gx) {
    const int BM = 128, BN = 80, BK = 16;
    __shared__ float As[BK][BM];
    __shared__ float Bs[BK][BN];
    int m0 = blockIdx.y * BM;
    int n0 = blockIdx.x * BN;
    int tid = threadIdx.x;
    int tm = tid >> 4, tn = tid & 15;
    float acc[8][5];
#pragma unroll
    for (int i = 0; i < 8; ++i)
#pragma unroll
        for (int j = 0; j < 5; ++j) acc[i][j] = 0.f;

    for (int k0 = 0; k0 < INDIM; k0 += BK) {
        {
            int row = tid >> 1, kk = (tid & 1) * 8;
            const float* ap = x + (size_t)(m0 + row) * INDIM + k0 + kk;
#pragma unroll
            for (int i = 0; i < 8; ++i)
                As[kk + i][row] = (k0 + kk + i < INDIM) ? ap[i] : 0.f;
        }
        if (tid < 160) {
            int col = tid >> 1, kk = (tid & 1) * 8;
            const float* bp = W_ih + (size_t)(n0 + col) * INDIM + k0 + kk;
#pragma unroll
            for (int i = 0; i < 8; ++i)
                Bs[kk + i][col] = (k0 + kk + i < INDIM) ? bp[i] : 0.f;
        }
        __syncthreads();
#pragma unroll
        for (int k = 0; k < BK; ++k) {
            float a[8], b[5];
#pragma unroll
            for (int i = 0; i < 8; ++i) a[i] = As[k][tm * 8 + i];
#pragma unroll
            for (int j = 0; j < 5; ++j) b[j] = Bs[k][tn * 5 + j];
#pragma unroll
            for (int i = 0; i < 8; ++i)
#pragma unroll
                for (int j = 0; j < 5; ++j) acc[i][j] += a[i] * b[j];
        }
        __syncthreads();
    }
#pragma unroll
    for (int j = 0; j < 5; ++j) {
        int n = n0 + tn * 5 + j;
        float bias = b_ih[n] + b_hh[n];
#pragma unroll
        for (int i = 0; i < 8; ++i) {
            int m = m0 + tm * 8 + i;
            gx[(size_t)m * G4H + n] = acc[i][j] + bias;
        }
    }
}

// ---------------- persistent NTM scan: NG=2, 512 thr, 2 blocks/CU ----------
__global__ __launch_bounds__(512, 4) void ntm_scan(
        const float* __restrict__ gx,          // [T][B][800]
        const uint4* __restrict__ Whh_q4,      // [50][400] quad-packed bf16
        const uint2* __restrict__ Wk_q2,       // [50][160] quad-packed bf16
        const float* __restrict__ bk,
        const float* __restrict__ Wsm,         // [4][200]
        const float* __restrict__ bs,
        const float* __restrict__ Wo,          // [5][360]
        const float* __restrict__ bo,
        float* __restrict__ out) {             // [T][B][5]
    __shared__ float sM[NG][NMEM][DPAD];
    __shared__ float sh[NG][HDIM];
    __shared__ float sgate[NG][G4H];
    __shared__ float spartK[NG][2][RD];
    __shared__ float spartS[NG][RH][4];
    __shared__ float swr[NG][RH][NMEM];
    __shared__ float sww[NG][RH][NMEM];
    __shared__ float sKs[NG][RH][NMEM];
    __shared__ float swu[NG][NMEM];
    __shared__ float swlu[NG][NMEM];
    __shared__ float sk[NG][RH][DMEM];
    __shared__ float sr[NG][RD];
    __shared__ float snk[NG][RH];
    __shared__ float ssig[NG][RH];
    __shared__ float snM[NG][NMEM];
    __shared__ float stmp[NG][NWAY];
    __shared__ int   sidx[NG];

    const int tid = threadIdx.x;
    const int b0  = blockIdx.x * NG;
    const int w   = tid >> 6, l = tid & 63;

    // ---- init carries ----
    for (int e = tid; e < NG * NMEM * DPAD; e += 512) ((float*)sM)[e] = 0.f;
    for (int e = tid; e < NG * HDIM; e += 512) ((float*)sh)[e] = 0.f;
    for (int e = tid; e < NG * RH * NMEM; e += 512) ((float*)swr)[e] = 0.f;
    for (int e = tid; e < NG * NMEM; e += 512) { ((float*)swu)[e] = 0.f; ((float*)swlu)[e] = 1.f; }

    float c_reg = 0.f;
    float gxr0 = 0.f, gxr1 = 0.f, gxr2 = 0.f, gxr3 = 0.f;
    int pg = 0, pj = 0;
    if (tid < NG * HDIM) {
        pg = tid / HDIM; pj = tid - pg * HDIM;
        const float* gxp = gx + (size_t)(b0 + pg) * G4H + pj;
        gxr0 = gxp[0]; gxr1 = gxp[HDIM]; gxr2 = gxp[2 * HDIM]; gxr3 = gxp[3 * HDIM];
    }
    __syncthreads();

    for (int t = 0; t < TSTEPS; ++t) {
        // ---- A: raw gates = h @ WhhT (400 thr; 50 x dwordx4 weight loads) ----
        if (tid < 400) {
            const uint4* wq = Whh_q4 + tid;
            float a00 = 0.f, a01 = 0.f, a10 = 0.f, a11 = 0.f;
#pragma unroll 5
            for (int jq = 0; jq < 50; ++jq) {
                uint4 wv = wq[jq * 400];
                float4 h0 = *(const float4*)&sh[0][jq * 4];
                float4 h1 = *(const float4*)&sh[1][jq * 4];
                float we0 = bflo(wv.x), we1 = bfhi(wv.x);
                float wo0 = bflo(wv.y), wo1 = bfhi(wv.y);
                float we2 = bflo(wv.z), we3 = bfhi(wv.z);
                float wo2 = bflo(wv.w), wo3 = bfhi(wv.w);
                a00 += we0 * h0.x + we1 * h0.y + we2 * h0.z + we3 * h0.w;
                a01 += wo0 * h0.x + wo1 * h0.y + wo2 * h0.z + wo3 * h0.w;
                a10 += we0 * h1.x + we1 * h1.y + we2 * h1.z + we3 * h1.w;
                a11 += wo0 * h1.x + wo1 * h1.y + wo2 * h1.z + wo3 * h1.w;
            }
            sgate[0][2 * tid]     = a00;
            sgate[0][2 * tid + 1] = a01;
            sgate[1][2 * tid]     = a10;
            sgate[1][2 * tid + 1] = a11;
        }
        __syncthreads();

        // ---- B: LSTM cell (400 thr); c in regs; prefetch next gx ----
        if (tid < NG * HDIM) {
            float ig = sigmoidf_(sgate[pg][pj] + gxr0);
            float fg = sigmoidf_(sgate[pg][pj + HDIM] + gxr1);
            float gv = ftanh(sgate[pg][pj + 2 * HDIM] + gxr2);
            float og = sigmoidf_(sgate[pg][pj + 3 * HDIM] + gxr3);
            c_reg = fg * c_reg + ig * gv;
            sh[pg][pj] = og * ftanh(c_reg);
            if (t + 1 < TSTEPS) {
                const float* gxp = gx + ((size_t)(t + 1) * BATCH + b0 + pg) * G4H + pj;
                gxr0 = gxp[0]; gxr1 = gxp[HDIM]; gxr2 = gxp[2 * HDIM]; gxr3 = gxp[3 * HDIM];
            }
        }
        __syncthreads();

        // ---- C: key partials (320; 25 x dwordx2/chunk) | argmin (128) | sigma (32) ----
        if (tid < 320) {
            int col = tid % RD, c = tid / RD;   // 2 K-chunks of 100 (25 quads)
            const uint2* wq = Wk_q2 + (size_t)(c * 25) * RD + col;
            const int jb = c * 100;
            float a0 = 0.f, a1 = 0.f;
#pragma unroll 5
            for (int q = 0; q < 25; ++q) {
                uint2 wv = wq[q * RD];
                float4 h0 = *(const float4*)&sh[0][jb + q * 4];
                float4 h1 = *(const float4*)&sh[1][jb + q * 4];
                float w0 = bflo(wv.x), w1 = bfhi(wv.x);
                float w2 = bflo(wv.y), w3 = bfhi(wv.y);
                a0 += w0 * h0.x + w1 * h0.y + w2 * h0.z + w3 * h0.w;
                a1 += w0 * h1.x + w1 * h1.y + w2 * h1.z + w3 * h1.w;
            }
            spartK[0][c][col] = a0;
            spartK[1][c][col] = a1;
        } else if (tid < 448) {
            int a = tid - 320; int g = a >> 6, ln = a & 63;   // waves 5,6
            float v0 = swu[g][ln], v1 = swu[g][ln + 64];
            bool p1 = (v1 < v0);
            float mv = p1 ? v1 : v0;
            int   mi = p1 ? ln + 64 : ln;
#pragma unroll
            for (int off = 32; off; off >>= 1) {
                float ov = __shfl_xor(mv, off);
                int   oi = __shfl_xor(mi, off);
                if (ov < mv || (ov == mv && oi < mi)) { mv = ov; mi = oi; }
            }
            if (ln == 0) sidx[g] = mi;
        } else if (tid < 480) {
            int v = tid - 448; int g = v >> 4, rc = v & 15, r = rc >> 2, cc = rc & 3;
            const float* wrow = Wsm + r * HDIM;
            float a = 0.f;
            for (int j = 50 * cc; j < 50 * cc + 50; ++j) a += sh[g][j] * wrow[j];
            spartS[g][r][cc] = a;
        }
        __syncthreads();

        // ---- D: finalize k (320) | finalize sigma (8) ----
        if (tid < 320) {
            int g = tid / RD, col = tid % RD;
            float s = spartK[g][0][col] + spartK[g][1][col] + bk[col];
            sk[g][col / DMEM][col % DMEM] = ftanh(s);
        } else if (tid < 328) {
            int v = tid - 320; int g = v >> 2, r = v & 3;
            float s = spartS[g][r][0] + spartS[g][r][1]
                    + spartS[g][r][2] + spartS[g][r][3] + bs[r];
            ssig[g][r] = sigmoidf_(ftanh(s));
        }
        __syncthreads();

        // ---- E2': ww + zero-LU-row + rank-4 M update (512) ; ||k|| (8) ----
        {
            int g = tid >> 8, mh = tid & 255, m = mh >> 1, dh = mh & 1;
            float sg0 = ssig[g][0], sg1 = ssig[g][1], sg2 = ssig[g][2], sg3 = ssig[g][3];
            float wl = swlu[g][m];
            float w0 = sg0 * swr[g][0][m] + (1.f - sg0) * wl;
            float w1 = sg1 * swr[g][1][m] + (1.f - sg1) * wl;
            float w2 = sg2 * swr[g][2][m] + (1.f - sg2) * wl;
            float w3 = sg3 * swr[g][3][m] + (1.f - sg3) * wl;
            if (!dh) {
                sww[g][0][m] = w0; sww[g][1][m] = w1;
                sww[g][2][m] = w2; sww[g][3][m] = w3;
            }
            bool zr = (m == sidx[g]);
            int d0 = dh * 20;
#pragma unroll
            for (int q = 0; q < 5; ++q) {
                int d = d0 + q * 4;
                float4 mv = *(const float4*)&sM[g][m][d];
                float4 k0 = *(const float4*)&sk[g][0][d];
                float4 k1 = *(const float4*)&sk[g][1][d];
                float4 k2 = *(const float4*)&sk[g][2][d];
                float4 k3 = *(const float4*)&sk[g][3][d];
                float4 o;
                o.x = (zr ? 0.f : mv.x) + w0 * k0.x + w1 * k1.x + w2 * k2.x + w3 * k3.x;
                o.y = (zr ? 0.f : mv.y) + w0 * k0.y + w1 * k1.y + w2 * k2.y + w3 * k3.y;
                o.z = (zr ? 0.f : mv.z) + w0 * k0.z + w1 * k1.z + w2 * k2.z + w3 * k3.z;
                o.w = (zr ? 0.f : mv.w) + w0 * k0.w + w1 * k1.w + w2 * k2.w + w3 * k3.w;
                *(float4*)&sM[g][m][d] = o;
            }
            if (tid < 8) {
                int g2 = tid >> 2, r2 = tid & 3;
                float a0 = 0.f, a1 = 0.f, a2 = 0.f, a3 = 0.f;
#pragma unroll
                for (int q = 0; q < 10; ++q) {
                    float4 kv = *(const float4*)&sk[g2][r2][q * 4];
                    a0 += kv.x * kv.x; a1 += kv.y * kv.y;
                    a2 += kv.z * kv.z; a3 += kv.w * kv.w;
                }
                snk[g2][r2] = sqrtf((a0 + a1) + (a2 + a3));
            }
        }
        __syncthreads();

        // ---- NF: raw cosine dots (2x512) + M row norms (256) ----
#pragma unroll
        for (int q = 0; q < 2; ++q) {
            int e = tid + q * 512;
            int g = e >> 9, rm = e & 511, r = rm >> 7, m = rm & 127;
            float a0 = 0.f, a1 = 0.f, a2 = 0.f, a3 = 0.f;
#pragma unroll
            for (int d4 = 0; d4 < 10; ++d4) {
                float4 kv = *(const float4*)&sk[g][r][d4 * 4];
                float4 mv = *(const float4*)&sM[g][m][d4 * 4];
                a0 += kv.x * mv.x; a1 += kv.y * mv.y;
                a2 += kv.z * mv.z; a3 += kv.w * mv.w;
            }
            sKs[g][r][m] = (a0 + a1) + (a2 + a3);
        }
        if (tid < 256) {
            int g = tid >> 7, m = tid & 127;
            float a0 = 0.f, a1 = 0.f, a2 = 0.f, a3 = 0.f;
#pragma unroll
            for (int d4 = 0; d4 < 10; ++d4) {
                float4 mv = *(const float4*)&sM[g][m][d4 * 4];
                a0 += mv.x * mv.x; a1 += mv.y * mv.y;
                a2 += mv.z * mv.z; a3 += mv.w * mv.w;
            }
            snM[g][m] = sqrtf((a0 + a1) + (a2 + a3));
        }
        __syncthreads();

        // ---- G: cosine normalize + softmax over m -> wr_new (8 waves) ----
        {
            int g = w >> 2, r = w & 3, ln = l;
            float ink = snk[g][r];
            float a = sKs[g][r][ln] / (ink * snM[g][ln]);
            float b = sKs[g][r][ln + 64] / (ink * snM[g][ln + 64]);
            float mx = fmaxf(a, b);
#pragma unroll
            for (int off = 32; off; off >>= 1) mx = fmaxf(mx, __shfl_xor(mx, off));
            float ea = __expf(a - mx), eb = __expf(b - mx);
            float s = ea + eb;
#pragma unroll
            for (int off = 32; off; off >>= 1) s += __shfl_xor(s, off);
            float inv = 1.f / s;
            swr[g][r][ln]      = ea * inv;
            swr[g][r][ln + 64] = eb * inv;
        }
        __syncthreads();

        // ---- H: read vectors (80, float4) | usage update (256) ----
        if (tid < 80) {
            int g = tid / 40, rd4 = tid % 40, r = rd4 / 10, d4 = rd4 % 10;
            float a0 = 0.f, a1 = 0.f, a2 = 0.f, a3 = 0.f;
            for (int m = 0; m < NMEM; ++m) {
                float wv = swr[g][r][m];
                float4 mv = *(const float4*)&sM[g][m][d4 * 4];
                a0 += wv * mv.x; a1 += wv * mv.y;
                a2 += wv * mv.z; a3 += wv * mv.w;
            }
            float4 res = {a0, a1, a2, a3};
            *(float4*)&sr[g][r * DMEM + d4 * 4] = res;
        } else if (tid >= 256) {
            int e = tid - 256;
            int g = e >> 7, m = e & 127;
            float wu = GAMMA_ * swu[g][m];
#pragma unroll
            for (int r = 0; r < RH; ++r) wu += swr[g][r][m] + sww[g][r][m];
            swu[g][m] = wu;
        }
        __syncthreads();

        // ---- I1: output head GEMV (320) | kth-smallest + wlu (128) ----
        if (tid < 320) {
            int g = tid / RD, v = tid % RD, o = v >> 5, ln = v & 31;
            const float* wrow = Wo + o * (HDIM + RD);
            float acc = 0.f;
            for (int j = ln; j < HDIM; j += 32) acc += sh[g][j] * wrow[j];
            for (int d = ln; d < RD; d += 32) acc += sr[g][d] * wrow[HDIM + d];
#pragma unroll
            for (int off = 16; off; off >>= 1) acc += __shfl_xor(acc, off, 32);
            if (ln == 0) stmp[g][o] = acc + bo[o];
        } else if (tid < 448) {
            int a = tid - 320; int g = a >> 6, ln = a & 63;   // waves 5,6
            float o0 = swu[g][ln], o1 = swu[g][ln + 64];
            float v0 = o0, v1 = o1, kth = 0.f;
#pragma unroll
            for (int it = 0; it < RH; ++it) {
                bool p1 = (v1 < v0);
                float mv = p1 ? v1 : v0;
                int   mi = p1 ? ln + 64 : ln;
                for (int off = 32; off; off >>= 1) {
                    float ov = __shfl_xor(mv, off);
                    int   oi = __shfl_xor(mi, off);
                    if (ov < mv || (ov == mv && oi < mi)) { mv = ov; mi = oi; }
                }
                kth = mv;
                if (mi == ln) v0 = __builtin_inff();
                else if (mi == ln + 64) v1 = __builtin_inff();
            }
            swlu[g][ln]      = (o0 <= kth) ? 1.f : 0.f;
            swlu[g][ln + 64] = (o1 <= kth) ? 1.f : 0.f;
        }
        __syncthreads();

        // ---- I2: final sigmoid+softmax + store (no trailing barrier) ----
        if (tid < NG) {
            int g = tid;
            float v[NWAY], mx = -1e30f;
#pragma unroll
            for (int o = 0; o < NWAY; ++o) { v[o] = sigmoidf_(stmp[g][o]); mx = fmaxf(mx, v[o]); }
            float s = 0.f;
#pragma unroll
            for (int o = 0; o < NWAY; ++o) { v[o] = __expf(v[o] - mx); s += v[o]; }
            float inv = 1.f / s;
            float* op = out + ((size_t)t * BATCH + (b0 + g)) * NWAY;
#pragma unroll
            for (int o = 0; o < NWAY; ++o) op[o] = v[o] * inv;
        }
    }
}

extern "C" void kernel_launch(void* const* d_in, const int* in_sizes, int n_in,
                              void* d_out, int out_size, void* d_ws, size_t ws_size,
                              hipStream_t stream) {
    const float* x    = (const float*)d_in[0];
    const float* W_ih = (const float*)d_in[1];
    const float* W_hh = (const float*)d_in[2];
    const float* b_ih = (const float*)d_in[3];
    const float* b_hh = (const float*)d_in[4];
    const float* Wk   = (const float*)d_in[5];
    const float* bk   = (const float*)d_in[6];
    const float* Wsm  = (const float*)d_in[7];
    const float* bs   = (const float*)d_in[8];
    const float* Wo   = (const float*)d_in[9];
    const float* bo   = (const float*)d_in[10];
    float* out = (float*)d_out;

    const size_t gx_elems  = (size_t)TSTEPS * BATCH * G4H;  // 40,960,000 f32
    const size_t whh_q4_e  = (size_t)50 * 400;              // uint4 (16B)
    const size_t wk_q2_e   = (size_t)50 * 160;              // uint2 (8B)
    const size_t a_elems   = (size_t)TSTEPS * BATCH * KP;   // u16 each
    const size_t w_elems   = (size_t)2 * WROWS * KP;        // u16
    const size_t need_base = gx_elems * 4 + whh_q4_e * 16 + wk_q2_e * 8;
    const size_t need_mfma = need_base + (2 * a_elems + w_elems) * 2;
    if (ws_size < need_base) return;

    float* gxb = (float*)d_ws;
    uint4* Whh_q4 = (uint4*)(gxb + gx_elems);          // 16B-aligned (gx bytes %16==0)
    uint2* Wk_q2  = (uint2*)(Whh_q4 + whh_q4_e);

    {
        int tot = (int)(whh_q4_e + wk_q2_e);
        convert_recQ<<<dim3((tot + 255) / 256), dim3(256), 0, stream>>>(W_hh, Wk, Whh_q4, Wk_q2);
    }

    if (ws_size >= need_mfma) {
        unsigned short* Ahi = (unsigned short*)(Wk_q2 + wk_q2_e);
        unsigned short* Alo = Ahi + a_elems;
        unsigned short* Wpk = Alo + a_elems;
        convert_A<<<dim3(2, TSTEPS * BATCH), dim3(256), 0, stream>>>(x, Ahi, Alo);
        convert_W<<<dim3(2, WROWS, 2), dim3(256), 0, stream>>>(W_ih, Wpk);
        gx_gemm_mfma<<<dim3(7, (TSTEPS * BATCH) / 128), dim3(256), 0, stream>>>(
            Ahi, Alo, Wpk, b_ih, b_hh, gxb);
    } else {
        gx_gemm<<<dim3(G4H / 80, (TSTEPS * BATCH) / 128), dim3(256), 0, stream>>>(
            x, W_ih, b_ih, b_hh, gxb);
    }

    ntm_scan<<<dim3(BATCH / NG), dim3(512), 0, stream>>>(
        gxb, Whh_q4, Wk_q2, bk, Wsm, bs, Wo, bo, out);
}